// Round 1
// baseline (7780.475 us; speedup 1.0000x reference)
//
#include <hip/hip_runtime.h>
#include <hip/hip_bf16.h>

#define TT 512
#define BB 256
#define II 13
#define HH 512
#define KP 544              // padded K: [0,512)=h, [512,525)=x, 525=1.0 (bias), rest 0
#define NBLK 256
#define NTH 256
#define PS (BB * KP)        // elems per (buf,plane): 139264
#define NKT 17              // K tiles of 32
#define PF 4                // A prefetch depth

typedef __attribute__((ext_vector_type(8))) short short8;
typedef __attribute__((ext_vector_type(4))) float floatx4;

__device__ inline float sigm(float v) { return 1.f / (1.f + __expf(-v)); }
__device__ inline float tanh_(float v) {
    float e = __expf(-2.f * fabsf(v));
    float t = (1.f - e) / (1.f + e);
    return v < 0.f ? -t : t;
}
__device__ inline void split_bf16(float v, __hip_bfloat16* hi, __hip_bfloat16* lo) {
    __hip_bfloat16 h = __float2bfloat16(v);
    *hi = h;
    *lo = __float2bfloat16(v - __bfloat162float(h));
}

// spin barrier: monotonically increasing counter, target = members*phase.
// Bounded spin: a pathological stall yields a wrong answer, never a hang.
__device__ inline void barrier_dev(unsigned* cnt, unsigned target) {
    __syncthreads();
    if (threadIdx.x == 0) {
        __threadfence();  // release: drain + wbL2 so other XCDs can see our h stores
        __hip_atomic_fetch_add(cnt, 1u, __ATOMIC_RELAXED, __HIP_MEMORY_SCOPE_AGENT);
        int guard = 0;
        while (__hip_atomic_load(cnt, __ATOMIC_RELAXED, __HIP_MEMORY_SCOPE_AGENT) < target &&
               ++guard < (1 << 14)) { }
        __threadfence();  // acquire: invalidate L1/L2 so we read fresh h
    }
    __syncthreads();
}

__global__ void __launch_bounds__(NTH, 1)
lstm_persist(const float* __restrict__ X,   const float* __restrict__ Wih,
             const float* __restrict__ Whh, const float* __restrict__ bih,
             const float* __restrict__ bhh, const float* __restrict__ Wout,
             const float* __restrict__ bout, float* __restrict__ Y,
             __hip_bfloat16* __restrict__ hbuf, unsigned* __restrict__ bars)
{
    extern __shared__ char smem[];
    __hip_bfloat16* Wshi = (__hip_bfloat16*)smem;     // [64][KP] hi
    __hip_bfloat16* Wslo = Wshi + 64 * KP;            // [64][KP] lo
    float* gbuf = (float*)(Wslo + 64 * KP);           // [4][32][16] gate staging

    const int tid  = threadIdx.x;
    const int bx   = blockIdx.x;
    const int bc   = bx & 7;    // batch chunk (32 rows)  -> XCD under %8 heuristic
    const int hs   = bx >> 3;   // hidden slice (16 units)
    const int lane = tid & 63;
    const int wid  = tid >> 6;

    unsigned* gcnt = bars + 256;       // global barrier counter
    unsigned* bcnt = bars + bc * 32;   // per-batch-chunk counter (128B spaced)

    // ---- phase 0: zero both aug buffers (hi+lo), init Y = b_out ----
    {
        const float b0 = bout[0];
        for (int i = bx * NTH + tid; i < 4 * PS; i += NBLK * NTH)
            hbuf[i] = __float2bfloat16(0.f);
        for (int i = bx * NTH + tid; i < TT * BB; i += NBLK * NTH)
            Y[i] = b0;
    }
    barrier_dev(gcnt, NBLK);

    // ---- phase 1: bias-one column, x_0, W slice -> LDS (hi/lo split) ----
    {
        int gid = bx * NTH + tid;
        if (gid < 2 * BB) {  // blocks 0,1: col 525 = 1.0 in hi plane, both buffers
            int buf = gid >> 8, b = gid & 255;
            hbuf[buf * 2 * PS + b * KP + (HH + II)] = __float2bfloat16(1.f);
        }
    }
    if (hs == 0) {  // x_0 into buffer 0
        for (int e = tid; e < 32 * II; e += NTH) {
            int bl = e / II, xc = e - bl * II;
            int b = bc * 32 + bl;
            float v = X[b * II + xc];
            __hip_bfloat16 hi, lo; split_bf16(v, &hi, &lo);
            hbuf[b * KP + HH + xc]      = hi;
            hbuf[PS + b * KP + HH + xc] = lo;
        }
    }
    for (int n = 0; n < 64; ++n) {   // 64 gate rows owned by this block
        int gate = n >> 4, hl = n & 15;
        int gr = gate * HH + hs * 16 + hl;   // global gate row (i,f,g,o order)
        for (int k = tid; k < KP; k += NTH) {
            float v;
            if (k < HH)            v = Whh[gr * HH + k];
            else if (k < HH + II)  v = Wih[gr * II + (k - HH)];
            else if (k == HH + II) v = bih[gr] + bhh[gr];
            else                   v = 0.f;
            __hip_bfloat16 hi, lo; split_bf16(v, &hi, &lo);
            Wshi[n * KP + k] = hi;
            Wslo[n * KP + k] = lo;
        }
    }
    barrier_dev(gcnt, 2 * NBLK);

    // ---- main recurrence ----
    const int mt = wid & 1;                  // batch 16-row half
    const int gp = wid >> 1;                 // gate pair {2gp, 2gp+1}
    const int arow  = bc * 32 + mt * 16 + (lane & 15);
    const int kgo   = (lane >> 4) * 8;       // k offset of this lane's 8 elems
    const int brow0 = (gp * 32 + (lane & 15)) * KP;
    const int brow1 = brow0 + 16 * KP;

    float c0 = 0.f, c1 = 0.f;                // cell state, 2 elems/thread
    const int ebl = tid >> 4;                // elementwise (b_loc, h) mapping
    const int eh  = tid & 15;
    const float wout = Wout[hs * 16 + eh];

    for (int t = 0; t < TT; ++t) {
        const int cur = t & 1, nxt = cur ^ 1;
        const __hip_bfloat16* Ahi = hbuf + cur * 2 * PS + arow * KP;
        const __hip_bfloat16* Alo = Ahi + PS;

        floatx4 acc0 = {0.f, 0.f, 0.f, 0.f};
        floatx4 acc1 = {0.f, 0.f, 0.f, 0.f};

        short8 ah[PF], al[PF];
#pragma unroll
        for (int p = 0; p < PF; ++p) {
            ah[p] = *(const short8*)(Ahi + p * 32 + kgo);
            al[p] = *(const short8*)(Alo + p * 32 + kgo);
        }
#pragma unroll
        for (int kt = 0; kt < NKT; ++kt) {
            const int k0 = kt * 32 + kgo;
            short8 chi = ah[kt % PF], clo = al[kt % PF];
            if (kt + PF < NKT) {
                ah[kt % PF] = *(const short8*)(Ahi + (kt + PF) * 32 + kgo);
                al[kt % PF] = *(const short8*)(Alo + (kt + PF) * 32 + kgo);
            }
            short8 bh0 = *(const short8*)(Wshi + brow0 + k0);
            short8 bl0 = *(const short8*)(Wslo + brow0 + k0);
            short8 bh1 = *(const short8*)(Wshi + brow1 + k0);
            short8 bl1 = *(const short8*)(Wslo + brow1 + k0);
            acc0 = __builtin_amdgcn_mfma_f32_16x16x32_bf16(chi, bh0, acc0, 0, 0, 0);
            acc1 = __builtin_amdgcn_mfma_f32_16x16x32_bf16(chi, bh1, acc1, 0, 0, 0);
            acc0 = __builtin_amdgcn_mfma_f32_16x16x32_bf16(chi, bl0, acc0, 0, 0, 0);
            acc1 = __builtin_amdgcn_mfma_f32_16x16x32_bf16(chi, bl1, acc1, 0, 0, 0);
            acc0 = __builtin_amdgcn_mfma_f32_16x16x32_bf16(clo, bh0, acc0, 0, 0, 0);
            acc1 = __builtin_amdgcn_mfma_f32_16x16x32_bf16(clo, bh1, acc1, 0, 0, 0);
        }
        {   // stage gate pre-activations to LDS  (D: row=(lane>>4)*4+r, col=lane&15)
            const int b0 = mt * 16 + (lane >> 4) * 4;
            const int g0 = gp * 2;
#pragma unroll
            for (int r = 0; r < 4; ++r) {
                gbuf[((g0    ) * 32 + b0 + r) * 16 + (lane & 15)] = acc0[r];
                gbuf[((g0 + 1) * 32 + b0 + r) * 16 + (lane & 15)] = acc1[r];
            }
        }
        __syncthreads();
        {   // elementwise: this thread owns (ebl, eh) and (ebl+16, eh)
            float gi0 = gbuf[(0 * 32 + ebl) * 16 + eh];
            float gf0 = gbuf[(1 * 32 + ebl) * 16 + eh];
            float gg0 = gbuf[(2 * 32 + ebl) * 16 + eh];
            float go0 = gbuf[(3 * 32 + ebl) * 16 + eh];
            float gi1 = gbuf[(0 * 32 + ebl + 16) * 16 + eh];
            float gf1 = gbuf[(1 * 32 + ebl + 16) * 16 + eh];
            float gg1 = gbuf[(2 * 32 + ebl + 16) * 16 + eh];
            float go1 = gbuf[(3 * 32 + ebl + 16) * 16 + eh];

            c0 = sigm(gf0) * c0 + sigm(gi0) * tanh_(gg0);
            float h0 = sigm(go0) * tanh_(c0);
            c1 = sigm(gf1) * c1 + sigm(gi1) * tanh_(gg1);
            float h1 = sigm(go1) * tanh_(c1);

            int b = bc * 32 + ebl;
            int kcol = hs * 16 + eh;
            __hip_bfloat16* base = hbuf + nxt * 2 * PS;
            __hip_bfloat16 hi, lo;
            split_bf16(h0, &hi, &lo);
            base[b * KP + kcol]      = hi;
            base[PS + b * KP + kcol] = lo;
            split_bf16(h1, &hi, &lo);
            base[(b + 16) * KP + kcol]      = hi;
            base[PS + (b + 16) * KP + kcol] = lo;

            float p0 = fmaxf(h0, 0.f) * wout;
            float p1 = fmaxf(h1, 0.f) * wout;
#pragma unroll
            for (int s = 8; s >= 1; s >>= 1) {
                p0 += __shfl_xor(p0, s);
                p1 += __shfl_xor(p1, s);
            }
            if (eh == 0) {
                atomicAdd(&Y[t * BB + b], p0);
                atomicAdd(&Y[t * BB + b + 16], p1);
            }
        }
        if (hs == 0 && t + 1 < TT) {   // stage x_{t+1} into next buffer
            __hip_bfloat16* base = hbuf + nxt * 2 * PS;
            for (int e = tid; e < 32 * II; e += NTH) {
                int bl = e / II, xc = e - bl * II;
                int b = bc * 32 + bl;
                float v = X[((t + 1) * BB + b) * II + xc];
                __hip_bfloat16 hi, lo; split_bf16(v, &hi, &lo);
                base[b * KP + HH + xc]      = hi;
                base[PS + b * KP + HH + xc] = lo;
            }
        }
        barrier_dev(bcnt, 32u * (unsigned)(t + 1));
    }
}

extern "C" void kernel_launch(void* const* d_in, const int* in_sizes, int n_in,
                              void* d_out, int out_size, void* d_ws, size_t ws_size,
                              hipStream_t stream) {
    (void)in_sizes; (void)n_in; (void)out_size; (void)ws_size;
    const float* X    = (const float*)d_in[0];
    const float* Wih  = (const float*)d_in[1];
    const float* Whh  = (const float*)d_in[2];
    const float* bih  = (const float*)d_in[3];
    const float* bhh  = (const float*)d_in[4];
    const float* Wout = (const float*)d_in[5];
    const float* bout = (const float*)d_in[6];
    float* Y = (float*)d_out;

    unsigned* bars = (unsigned*)d_ws;                              // [0, 2048)
    __hip_bfloat16* hbuf = (__hip_bfloat16*)((char*)d_ws + 2048);  // 2*2*256*544 bf16

    hipMemsetAsync(d_ws, 0, 2048, stream);  // reset barrier counters each call

    const size_t lds = (size_t)(64 * KP * 2 * 2) + 4 * 32 * 16 * 4;  // 147456
    hipFuncSetAttribute((const void*)lstm_persist,
                        hipFuncAttributeMaxDynamicSharedMemorySize, (int)lds);

    hipLaunchKernelGGL(lstm_persist, dim3(NBLK), dim3(NTH), lds, stream,
                       X, Wih, Whh, bih, bhh, Wout, bout, Y, hbuf, bars);
}

// Round 5
// 4431.405 us; speedup vs baseline: 1.7558x; 1.7558x over previous
//
#include <hip/hip_runtime.h>
#include <hip/hip_bf16.h>

#define TT 512
#define BB 256
#define II 13
#define HH 512
#define KP 544              // logical K: [0,512)=h, [512,525)=x, 525=1.0 (bias), rest 0
#define KPL 552             // LDS W row stride (bank spread)
#define NBLK 256
#define NTH 256
#define PS (BB * KP)        // elems per (buf,plane): 139264
#define NKT 17              // K tiles of 32
#define GST 18              // gbuf row stride (floats)
#define XROW (BB * II)      // 3328

typedef __attribute__((ext_vector_type(8))) short short8;
typedef __attribute__((ext_vector_type(4))) float floatx4;
typedef __attribute__((ext_vector_type(4))) int intx4;

__device__ inline float sigm(float v) { return 1.f / (1.f + __expf(-v)); }
__device__ inline float tanh_(float v) {
    float e = __expf(-2.f * fabsf(v));
    float t = (1.f - e) / (1.f + e);
    return v < 0.f ? -t : t;
}
__device__ inline void split_bits(float v, unsigned short* hi, unsigned short* lo) {
    __hip_bfloat16 h = __float2bfloat16(v);
    float r = v - __bfloat162float(h);
    __hip_bfloat16 l = __float2bfloat16(r);
    *hi = __builtin_bit_cast(unsigned short, h);
    *lo = __builtin_bit_cast(unsigned short, l);
}

// ---- MALL-direct (uncached) access path: sc0 sc1 bypasses vL1 AND L2.
// This is the ONE path empirically validated by R4's fast barrier. All
// cross-block data (hbuf) now travels it; no cache-maintenance ops anywhere.
__device__ inline unsigned poll_mall(const unsigned* p) {
    unsigned v;
    asm volatile("global_load_dword %0, %1, off sc0 sc1\n\ts_waitcnt vmcnt(0)"
                 : "=v"(v) : "v"(p) : "memory");
    return v;
}
__device__ inline void arrive_mall(unsigned* p) {
    asm volatile("global_atomic_add %0, %1, off sc1" :: "v"(p), "v"(1u) : "memory");
}
__device__ inline intx4 load_b128_uc(const void* p) {   // issue only; NO waitcnt
    intx4 v;
    asm volatile("global_load_dwordx4 %0, %1, off sc0 sc1" : "=v"(v) : "v"(p));
    return v;
}
__device__ inline void store_short_uc(void* p, unsigned short v) {
    unsigned vv = v;
    asm volatile("global_store_short %0, %1, off sc0 sc1" :: "v"(p), "v"(vv) : "memory");
}
__device__ inline void store_dword_uc(void* p, unsigned v) {
    asm volatile("global_store_dword %0, %1, off sc0 sc1" :: "v"(p), "v"(v) : "memory");
}
__device__ inline void store_f32_wt(float* p, float v) {
    asm volatile("global_store_dword %0, %1, off sc0 sc1" :: "v"(p), "v"(v) : "memory");
}

// In-XCD barrier, counter at MALL. __syncthreads drains each wave's vmcnt, so
// all the block's sc0sc1 stores are AT THE MALL before tid0's arrive. Peers
// seeing count==target therefore see all h at MALL; their A-loads are sc0sc1
// (MALL-direct) so no invalidation is needed. Bounded spin: stall -> wrong
// answer, never a hang.
__device__ inline void barrier_xcd(unsigned* cnt, unsigned target) {
    __syncthreads();
    if (threadIdx.x == 0) {
        arrive_mall(cnt);
        int guard = 0;
        unsigned v;
        do { v = poll_mall(cnt); } while ((int)(v - target) < 0 && ++guard < (1 << 16));
    }
    __syncthreads();
}

__global__ void __launch_bounds__(NTH, 1)
lstm_persist(const float* __restrict__ X,   const float* __restrict__ Wih,
             const float* __restrict__ Whh, const float* __restrict__ bih,
             const float* __restrict__ bhh, const float* __restrict__ Wout,
             const float* __restrict__ bout, float* __restrict__ Y,
             __hip_bfloat16* __restrict__ hbuf, unsigned* __restrict__ bars)
{
    extern __shared__ char smem[];
    __hip_bfloat16* Wshi = (__hip_bfloat16*)smem;       // [64][KPL] hi
    __hip_bfloat16* Wslo = Wshi + 64 * KPL;             // [64][KPL] lo
    float* gbuf = (float*)(Wslo + 64 * KPL);            // [128][GST] gate staging
    int* shint = (int*)(gbuf + 128 * GST);

    const int tid = threadIdx.x;

    // ---- runtime role assignment: bc = physical XCD, hs = rank within XCD.
    // 150KB LDS forces 1 block/CU; 256 blocks on 256 CUs => exactly 32/XCD.
    if (tid == 0) {
        unsigned x = __builtin_amdgcn_s_getreg(20 | (3 << 11)) & 7u; // HW_REG_XCC_ID
        unsigned r = __hip_atomic_fetch_add(bars + 256 + x * 16, 1u,
                        __ATOMIC_RELAXED, __HIP_MEMORY_SCOPE_AGENT);
        shint[0] = (int)x;
        shint[1] = (int)(r & 31u);
    }
    __syncthreads();
    const int bc = shint[0];
    const int hs = shint[1];
    unsigned* bcnt = bars + bc * 32;

    // ---- init: OWN-ROW ONLY, all hbuf writes uncached (MALL-direct) ----
    {
        const int row = bc * 32 + hs;
        unsigned* hb32 = (unsigned*)hbuf;
        const int rw = row * (KP / 2);               // dword index of row base
        for (int i = tid; i < KP / 2; i += NTH) {    // zero 4 (buf,plane) images
            store_dword_uc(hb32 +               rw + i, 0u);
            store_dword_uc(hb32 + (PS / 2)    + rw + i, 0u);
            store_dword_uc(hb32 + PS          + rw + i, 0u);
            store_dword_uc(hb32 + PS + PS / 2 + rw + i, 0u);
        }
        const float b0 = bout[0];
        for (int i = tid; i < 16 * 32; i += NTH) {   // Y[hs*16..+16)[bc*32..+32)
            int tr = hs * 16 + (i >> 5), cb = bc * 32 + (i & 31);
            store_f32_wt(&Y[tr * BB + cb], b0);
        }
        __syncthreads();   // own-row zeroing done before bias/x writes
        if (tid == 0) {    // bias-one column, both buffers (bf16 1.0 = 0x3F80)
            store_short_uc(hbuf +          row * KP + (HH + II), 0x3F80u);
            store_short_uc(hbuf + 2 * PS + row * KP + (HH + II), 0x3F80u);
        }
        if (tid < II) {    // x_0 for own row, both planes
            unsigned short hi, lo; split_bits(X[row * II + tid], &hi, &lo);
            store_short_uc(hbuf +      row * KP + HH + tid, hi);
            store_short_uc(hbuf + PS + row * KP + HH + tid, lo);
        }
    }
    // ---- W slice -> LDS (hi/lo split), padded stride ----
    for (int n = 0; n < 64; ++n) {
        int gate = n >> 4, hl = n & 15;
        int gr = gate * HH + hs * 16 + hl;   // global gate row (i,f,g,o order)
        for (int k = tid; k < KP; k += NTH) {
            float v;
            if (k < HH)            v = Whh[gr * HH + k];
            else if (k < HH + II)  v = Wih[gr * II + (k - HH)];
            else if (k == HH + II) v = bih[gr] + bhh[gr];
            else                   v = 0.f;
            unsigned short hi, lo; split_bits(v, &hi, &lo);
            Wshi[n * KPL + k] = __builtin_bit_cast(__hip_bfloat16, hi);
            Wslo[n * KPL + k] = __builtin_bit_cast(__hip_bfloat16, lo);
        }
    }
    // ---- x_1 register preload (hs==1 stages x_1 at t=0) ----
    const int e0 = 2 * tid;
    const bool stv = (e0 < 32 * II);
    const int bl0 = e0 / II, xc0 = e0 - bl0 * II;
    const int e1 = e0 + 1;
    const int bl1 = e1 / II, xc1 = e1 - bl1 * II;
    float xr0 = 0.f, xr1 = 0.f;
    if (hs == 1 && stv) {
        const float2 v = *(const float2*)(X + XROW + bc * (32 * II) + e0);
        xr0 = v.x; xr1 = v.y;
    }

    barrier_xcd(bcnt, 32u);   // init done (epoch 1)

    // ---- main recurrence ----
    const int lane = tid & 63, wid = tid >> 6;
    const int mt = wid & 1;                 // batch 16-row half
    const int gp = wid >> 1;                // gate pair {2gp, 2gp+1}
    const int arow  = bc * 32 + mt * 16 + (lane & 15);
    const int kgo   = (lane >> 4) * 8;
    const int brow0 = (gp * 32 + (lane & 15)) * KPL;
    const int brow1 = brow0 + 16 * KPL;
    float c0 = 0.f, c1 = 0.f;
    const int ebl = tid >> 4;               // elementwise (b_loc, h) mapping
    const int eh  = tid & 15;
    const float wout = Wout[hs * 16 + eh];

    for (int t = 0; t < TT; ++t) {
        const int cur = t & 1, nxt = cur ^ 1;
        const short* Ahi = (const short*)hbuf + cur * 2 * PS + arow * KP;
        const short* Alo = Ahi + PS;

        // issue all 34 A-tile loads (MALL-direct), then one drain + sched fence
        intx4 ah[NKT], al[NKT];
#pragma unroll
        for (int kt = 0; kt < NKT; ++kt) {
            ah[kt] = load_b128_uc(Ahi + kt * 32 + kgo);
            al[kt] = load_b128_uc(Alo + kt * 32 + kgo);
        }
        asm volatile("s_waitcnt vmcnt(0)" ::: "memory");
        __builtin_amdgcn_sched_barrier(0);   // rule #18: keep MFMAs below waitcnt

        floatx4 aA0 = {0,0,0,0}, aB0 = {0,0,0,0}, aC0 = {0,0,0,0};
        floatx4 aA1 = {0,0,0,0}, aB1 = {0,0,0,0}, aC1 = {0,0,0,0};
#pragma unroll
        for (int kt = 0; kt < NKT; ++kt) {
            const int k0 = kt * 32 + kgo;
            short8 chi = __builtin_bit_cast(short8, ah[kt]);
            short8 clo = __builtin_bit_cast(short8, al[kt]);
            short8 bh0 = *(const short8*)(Wshi + brow0 + k0);
            short8 bv0 = *(const short8*)(Wslo + brow0 + k0);
            short8 bh1 = *(const short8*)(Wshi + brow1 + k0);
            short8 bv1 = *(const short8*)(Wslo + brow1 + k0);
            aA0 = __builtin_amdgcn_mfma_f32_16x16x32_bf16(chi, bh0, aA0, 0, 0, 0);
            aA1 = __builtin_amdgcn_mfma_f32_16x16x32_bf16(chi, bh1, aA1, 0, 0, 0);
            aB0 = __builtin_amdgcn_mfma_f32_16x16x32_bf16(chi, bv0, aB0, 0, 0, 0);
            aB1 = __builtin_amdgcn_mfma_f32_16x16x32_bf16(chi, bv1, aB1, 0, 0, 0);
            aC0 = __builtin_amdgcn_mfma_f32_16x16x32_bf16(clo, bh0, aC0, 0, 0, 0);
            aC1 = __builtin_amdgcn_mfma_f32_16x16x32_bf16(clo, bh1, aC1, 0, 0, 0);
        }
        floatx4 acc0 = aA0 + aB0 + aC0;
        floatx4 acc1 = aA1 + aB1 + aC1;

        {   // stage gates to LDS  (D frag: row=(lane>>4)*4+r, col=lane&15)
            const int b0r = mt * 16 + (lane >> 4) * 4;
            const int g0 = gp * 2;
#pragma unroll
            for (int r = 0; r < 4; ++r) {
                gbuf[((g0    ) * 32 + b0r + r) * GST + (lane & 15)] = acc0[r];
                gbuf[((g0 + 1) * 32 + b0r + r) * GST + (lane & 15)] = acc1[r];
            }
        }
        __syncthreads();
        __hip_bfloat16* hb = hbuf + nxt * 2 * PS;
        {   // elementwise: this thread owns (ebl, eh) and (ebl+16, eh)
            float gi0 = gbuf[(0 * 32 + ebl) * GST + eh];
            float gf0 = gbuf[(1 * 32 + ebl) * GST + eh];
            float gg0 = gbuf[(2 * 32 + ebl) * GST + eh];
            float go0 = gbuf[(3 * 32 + ebl) * GST + eh];
            float gi1 = gbuf[(0 * 32 + ebl + 16) * GST + eh];
            float gf1 = gbuf[(1 * 32 + ebl + 16) * GST + eh];
            float gg1 = gbuf[(2 * 32 + ebl + 16) * GST + eh];
            float go1 = gbuf[(3 * 32 + ebl + 16) * GST + eh];

            c0 = sigm(gf0) * c0 + sigm(gi0) * tanh_(gg0);
            float h0 = sigm(go0) * tanh_(c0);
            c1 = sigm(gf1) * c1 + sigm(gi1) * tanh_(gg1);
            float h1 = sigm(go1) * tanh_(c1);

            int b = bc * 32 + ebl;
            int kcol = hs * 16 + eh;
            unsigned short hi, lo;
            split_bits(h0, &hi, &lo);
            store_short_uc(hb +      b * KP + kcol, hi);
            store_short_uc(hb + PS + b * KP + kcol, lo);
            split_bits(h1, &hi, &lo);
            store_short_uc(hb +      (b + 16) * KP + kcol, hi);
            store_short_uc(hb + PS + (b + 16) * KP + kcol, lo);

            float p0 = fmaxf(h0, 0.f) * wout;
            float p1 = fmaxf(h1, 0.f) * wout;
#pragma unroll
            for (int s = 8; s >= 1; s >>= 1) {
                p0 += __shfl_xor(p0, s);
                p1 += __shfl_xor(p1, s);
            }
            if (eh == 0) {
                atomicAdd(&Y[t * BB + b], p0);
                atomicAdd(&Y[t * BB + b + 16], p1);
            }
        }
        // rotating x-stager: owner of time s stages at t=s-1 from regs
        // preloaded at t=s-2 (HBM latency hidden under a full step)
        if (t + 1 < TT && hs == ((t + 1) & 31) && stv) {
            unsigned short hi, lo;
            split_bits(xr0, &hi, &lo);
            store_short_uc(hb +      (bc * 32 + bl0) * KP + HH + xc0, hi);
            store_short_uc(hb + PS + (bc * 32 + bl0) * KP + HH + xc0, lo);
            split_bits(xr1, &hi, &lo);
            store_short_uc(hb +      (bc * 32 + bl1) * KP + HH + xc1, hi);
            store_short_uc(hb + PS + (bc * 32 + bl1) * KP + HH + xc1, lo);
        }
        if (t + 2 < TT && hs == ((t + 2) & 31) && stv) {
            const float2 v = *(const float2*)(X + (t + 2) * XROW + bc * (32 * II) + e0);
            xr0 = v.x; xr1 = v.y;
        }
        if (t + 1 < TT)
            barrier_xcd(bcnt, 32u * (unsigned)(t + 2));
    }
}

extern "C" void kernel_launch(void* const* d_in, const int* in_sizes, int n_in,
                              void* d_out, int out_size, void* d_ws, size_t ws_size,
                              hipStream_t stream) {
    (void)in_sizes; (void)n_in; (void)out_size; (void)ws_size;
    const float* X    = (const float*)d_in[0];
    const float* Wih  = (const float*)d_in[1];
    const float* Whh  = (const float*)d_in[2];
    const float* bih  = (const float*)d_in[3];
    const float* bhh  = (const float*)d_in[4];
    const float* Wout = (const float*)d_in[5];
    const float* bout = (const float*)d_in[6];
    float* Y = (float*)d_out;

    unsigned* bars = (unsigned*)d_ws;                              // [0, 2048)
    __hip_bfloat16* hbuf = (__hip_bfloat16*)((char*)d_ws + 2048);  // 2 buf x 2 plane

    hipMemsetAsync(d_ws, 0, 2048, stream);

    const size_t lds = (size_t)(64 * KPL * 2 * 2) + 128 * GST * 4 + 16;  // 150544
    hipFuncSetAttribute((const void*)lstm_persist,
                        hipFuncAttributeMaxDynamicSharedMemorySize, (int)lds);

    hipLaunchKernelGGL(lstm_persist, dim3(NBLK), dim3(NTH), lds, stream,
                       X, Wih, Whh, bih, bhh, Wout, bout, Y, hbuf, bars);
}